// Round 2
// baseline (393.107 us; speedup 1.0000x reference)
//
#include <hip/hip_runtime.h>
#include <cmath>

#define B_ 2
#define H_ 8
#define S_ 2048
#define D_ 64
#define TS 64
#define LDST 68   // LDS row stride in floats (float4-aligned, bank-staggered)

// ---------------------------------------------------------------------------
// Kernel 1: per (b,h) compute avAp[f,e] = a_vec @ ((relu(W@A + b)+eps)^pw) + ba
// One block per (b,h). All f32 in LDS. Cost is negligible (~34 MFLOP total).
// ---------------------------------------------------------------------------
__global__ __launch_bounds__(256) void prep_avAp(
    const float* __restrict__ A, const float* __restrict__ W,
    const float* __restrict__ bb, const float* __restrict__ av,
    const float* __restrict__ ba, const float* __restrict__ pw,
    float* __restrict__ avAp)
{
    __shared__ float s0[TS * LDST];  // W, then Ap
    __shared__ float s1[TS * LDST];  // A, then a_vec
    const int tid = threadIdx.x;
    const int ty = tid >> 4, tx = tid & 15;
    const int bh = blockIdx.x;
    const int h = bh & (H_ - 1);

    const float4* W4 = (const float4*)(W + h * D_ * D_);
    const float4* A4 = (const float4*)(A + bh * D_ * D_);
#pragma unroll
    for (int it = 0; it < 4; ++it) {
        int idx = tid + it * 256;
        int r = idx >> 4, c = idx & 15;
        *(float4*)&s0[r * LDST + c * 4] = W4[idx];
        *(float4*)&s1[r * LDST + c * 4] = A4[idx];
    }
    __syncthreads();

    // M1 = W @ A   (rows from W, cols from A)
    float acc[4][4] = {};
    for (int d = 0; d < D_; ++d) {
        float4 a4 = *(const float4*)&s1[d * LDST + tx * 4];
#pragma unroll
        for (int i = 0; i < 4; ++i) {
            float w = s0[(ty * 4 + i) * LDST + d];
            acc[i][0] += w * a4.x; acc[i][1] += w * a4.y;
            acc[i][2] += w * a4.z; acc[i][3] += w * a4.w;
        }
    }
    __syncthreads();  // all reads of s0/s1 complete before overwrite

    // Ap = (relu(M1 + b) + eps)^pw  -> s0 ; stage a_vec -> s1
#pragma unroll
    for (int i = 0; i < 4; ++i) {
        int f = ty * 4 + i;
        float4 b4 = *(const float4*)&bb[(h * D_ + f) * D_ + tx * 4];
        float4 p4 = *(const float4*)&pw[(h * D_ + f) * D_ + tx * 4];
        float vb[4] = {b4.x, b4.y, b4.z, b4.w};
        float vp[4] = {p4.x, p4.y, p4.z, p4.w};
#pragma unroll
        for (int j = 0; j < 4; ++j) {
            float aw = fmaxf(acc[i][j] + vb[j], 0.f) + 1e-9f;
            s0[f * LDST + tx * 4 + j] = powf(aw, vp[j]);
        }
    }
    const float4* av4 = (const float4*)(av + h * D_ * D_);
#pragma unroll
    for (int it = 0; it < 4; ++it) {
        int idx = tid + it * 256;
        int r = idx >> 4, c = idx & 15;
        *(float4*)&s1[r * LDST + c * 4] = av4[idx];
    }
    __syncthreads();

    // avAp = a_vec @ Ap + ba
    float acc2[4][4] = {};
    for (int d = 0; d < D_; ++d) {
        float4 a4 = *(const float4*)&s0[d * LDST + tx * 4];
#pragma unroll
        for (int i = 0; i < 4; ++i) {
            float w = s1[(ty * 4 + i) * LDST + d];
            acc2[i][0] += w * a4.x; acc2[i][1] += w * a4.y;
            acc2[i][2] += w * a4.z; acc2[i][3] += w * a4.w;
        }
    }
#pragma unroll
    for (int i = 0; i < 4; ++i) {
        int f = ty * 4 + i;
        float4 ba4 = *(const float4*)&ba[(h * D_ + f) * D_ + tx * 4];
        float4 o = make_float4(acc2[i][0] + ba4.x, acc2[i][1] + ba4.y,
                               acc2[i][2] + ba4.z, acc2[i][3] + ba4.w);
        *(float4*)&avAp[bh * D_ * D_ + f * D_ + tx * 4] = o;
    }
}

// ---------------------------------------------------------------------------
// Kernel 2: flash attention, f32. One block per (b,h, 64-row Q tile).
// Qp = Hin_tile @ avAp computed in-block; online softmax over K/V tiles.
// K stored transposed in LDS so score-phase b128 reads are conflict-free.
// ---------------------------------------------------------------------------
__global__ __launch_bounds__(256) void flash(
    const float* __restrict__ Hin, const float* __restrict__ Hk,
    const float* __restrict__ Hv, const float* __restrict__ mask,
    const float* __restrict__ avAp, float* __restrict__ out)
{
    __shared__ float sQ[TS * LDST];
    __shared__ float sKT[TS * LDST];  // sKT[kk][c]: transposed K tile
    __shared__ float sV[TS * LDST];
    __shared__ float sP[TS * LDST];
    __shared__ float sMask[TS];

    const int tid = threadIdx.x;
    const int ty = tid >> 4, tx = tid & 15;
    const int qt = blockIdx.x;
    const int bh = blockIdx.y;
    const int bidx = bh >> 3;  // H_ = 8
    const size_t base = (size_t)bh * S_ * D_;
    const int q0 = qt * TS;

    // Stage avAp -> sKT (temp), Hin tile -> sV (temp)
    {
        const float4* a4 = (const float4*)(avAp + bh * D_ * D_);
        const float4* h4 = (const float4*)(Hin + base + (size_t)q0 * D_);
#pragma unroll
        for (int it = 0; it < 4; ++it) {
            int idx = tid + it * 256;
            int r = idx >> 4, c = idx & 15;
            *(float4*)&sKT[r * LDST + c * 4] = a4[idx];
            *(float4*)&sV[r * LDST + c * 4] = h4[idx];
        }
    }
    __syncthreads();

    // Qp = Hin_tile @ avAp -> sQ
    {
        float acc[4][4] = {};
        for (int f = 0; f < D_; ++f) {
            float4 a4 = *(const float4*)&sKT[f * LDST + tx * 4];
#pragma unroll
            for (int i = 0; i < 4; ++i) {
                float hval = sV[(ty * 4 + i) * LDST + f];
                acc[i][0] += hval * a4.x; acc[i][1] += hval * a4.y;
                acc[i][2] += hval * a4.z; acc[i][3] += hval * a4.w;
            }
        }
        __syncthreads();  // reads of sKT/sV done before they are reused
#pragma unroll
        for (int i = 0; i < 4; ++i)
            *(float4*)&sQ[(ty * 4 + i) * LDST + tx * 4] =
                make_float4(acc[i][0], acc[i][1], acc[i][2], acc[i][3]);
    }

    float m_run[4], l_run[4], Oa[4][4];
#pragma unroll
    for (int i = 0; i < 4; ++i) {
        m_run[i] = -1e30f; l_run[i] = 0.f;
#pragma unroll
        for (int j = 0; j < 4; ++j) Oa[i][j] = 0.f;
    }

    for (int kt = 0; kt < S_ / TS; ++kt) {
        __syncthreads();  // previous tile fully consumed before overwrite
        const float4* k4 = (const float4*)(Hk + base + (size_t)kt * TS * D_);
        const float4* v4 = (const float4*)(Hv + base + (size_t)kt * TS * D_);
#pragma unroll
        for (int it = 0; it < 4; ++it) {
            int idx = tid + it * 256;
            int r = idx >> 4, c = idx & 15;
            float4 kv = k4[idx];
            sKT[(c * 4 + 0) * LDST + r] = kv.x;
            sKT[(c * 4 + 1) * LDST + r] = kv.y;
            sKT[(c * 4 + 2) * LDST + r] = kv.z;
            sKT[(c * 4 + 3) * LDST + r] = kv.w;
            *(float4*)&sV[r * LDST + c * 4] = v4[idx];
        }
        if (tid < TS) sMask[tid] = -1e9f * mask[bidx * S_ + kt * TS + tid];
        __syncthreads();

        // scores: s[i][j] = dot(Qp row ty*4+i, K row tx*4+j)
        float s[4][4] = {};
        for (int k4i = 0; k4i < 16; ++k4i) {
            float4 q[4];
#pragma unroll
            for (int i = 0; i < 4; ++i)
                q[i] = *(const float4*)&sQ[(ty * 4 + i) * LDST + k4i * 4];
#pragma unroll
            for (int kk = 0; kk < 4; ++kk) {
                float4 kv = *(const float4*)&sKT[(k4i * 4 + kk) * LDST + tx * 4];
#pragma unroll
                for (int i = 0; i < 4; ++i) {
                    float qv = ((const float*)&q[i])[kk];
                    s[i][0] += qv * kv.x; s[i][1] += qv * kv.y;
                    s[i][2] += qv * kv.z; s[i][3] += qv * kv.w;
                }
            }
        }

        // scale /8, leaky_relu(0.2), +mask, online softmax
        float scale[4];
#pragma unroll
        for (int i = 0; i < 4; ++i) {
#pragma unroll
            for (int j = 0; j < 4; ++j) {
                float v = s[i][j] * 0.125f;
                v = (v > 0.f) ? v : 0.2f * v;
                s[i][j] = v + sMask[tx * 4 + j];
            }
            float m0 = fmaxf(fmaxf(s[i][0], s[i][1]), fmaxf(s[i][2], s[i][3]));
#pragma unroll
            for (int off = 1; off < 16; off <<= 1)
                m0 = fmaxf(m0, __shfl_xor(m0, off, 64));
            float mnew = fmaxf(m_run[i], m0);
            scale[i] = expf(m_run[i] - mnew);
            m_run[i] = mnew;
            float r0 = 0.f;
#pragma unroll
            for (int j = 0; j < 4; ++j) {
                float p = expf(s[i][j] - mnew);
                s[i][j] = p; r0 += p;
            }
#pragma unroll
            for (int off = 1; off < 16; off <<= 1)
                r0 += __shfl_xor(r0, off, 64);
            l_run[i] = l_run[i] * scale[i] + r0;
        }
#pragma unroll
        for (int i = 0; i < 4; ++i)
            *(float4*)&sP[(ty * 4 + i) * LDST + tx * 4] =
                make_float4(s[i][0], s[i][1], s[i][2], s[i][3]);
        __syncthreads();

        // O = O*scale + P @ V
#pragma unroll
        for (int i = 0; i < 4; ++i)
#pragma unroll
            for (int j = 0; j < 4; ++j) Oa[i][j] *= scale[i];
        for (int t4 = 0; t4 < 16; ++t4) {
            float4 p4[4];
#pragma unroll
            for (int i = 0; i < 4; ++i)
                p4[i] = *(const float4*)&sP[(ty * 4 + i) * LDST + t4 * 4];
#pragma unroll
            for (int tt = 0; tt < 4; ++tt) {
                float4 vv = *(const float4*)&sV[(t4 * 4 + tt) * LDST + tx * 4];
#pragma unroll
                for (int i = 0; i < 4; ++i) {
                    float p = ((const float*)&p4[i])[tt];
                    Oa[i][0] += p * vv.x; Oa[i][1] += p * vv.y;
                    Oa[i][2] += p * vv.z; Oa[i][3] += p * vv.w;
                }
            }
        }
    }

    // epilogue: normalize, relu, store
#pragma unroll
    for (int i = 0; i < 4; ++i) {
        float inv = 1.f / l_run[i];
        float4 o = make_float4(fmaxf(Oa[i][0] * inv, 0.f),
                               fmaxf(Oa[i][1] * inv, 0.f),
                               fmaxf(Oa[i][2] * inv, 0.f),
                               fmaxf(Oa[i][3] * inv, 0.f));
        *(float4*)&out[base + (size_t)(q0 + ty * 4 + i) * D_ + tx * 4] = o;
    }
}

extern "C" void kernel_launch(void* const* d_in, const int* in_sizes, int n_in,
                              void* d_out, int out_size, void* d_ws, size_t ws_size,
                              hipStream_t stream) {
    const float* Hin  = (const float*)d_in[0];
    const float* Hk   = (const float*)d_in[1];
    const float* Hv   = (const float*)d_in[2];
    const float* A    = (const float*)d_in[3];
    const float* mask = (const float*)d_in[4];
    const float* W    = (const float*)d_in[5];
    const float* bb   = (const float*)d_in[6];
    const float* av   = (const float*)d_in[7];
    const float* ba   = (const float*)d_in[8];
    const float* pw   = (const float*)d_in[9];
    float* out = (float*)d_out;
    float* ws  = (float*)d_ws;  // avAp: B*H*D*D floats = 256 KB

    prep_avAp<<<B_ * H_, 256, 0, stream>>>(A, W, bb, av, ba, pw, ws);
    flash<<<dim3(S_ / TS, B_ * H_), 256, 0, stream>>>(Hin, Hk, Hv, mask, ws, out);
}

// Round 3
// 306.850 us; speedup vs baseline: 1.2811x; 1.2811x over previous
//
#include <hip/hip_runtime.h>
#include <cmath>

#define B_ 2
#define H_ 8
#define S_ 2048
#define D_ 64
#define TS 64
#define LDST 68

typedef __attribute__((ext_vector_type(8))) _Float16 f16x8;
typedef __attribute__((ext_vector_type(4))) float f32x4;

// ---------------------------------------------------------------------------
// Kernel 1 (unchanged, verified R2): avAp = a_vec @ ((relu(W@A+b)+eps)^pw) + ba
// ---------------------------------------------------------------------------
__global__ __launch_bounds__(256) void prep_avAp(
    const float* __restrict__ A, const float* __restrict__ W,
    const float* __restrict__ bb, const float* __restrict__ av,
    const float* __restrict__ ba, const float* __restrict__ pw,
    float* __restrict__ avAp)
{
    __shared__ float s0[TS * LDST];
    __shared__ float s1[TS * LDST];
    const int tid = threadIdx.x;
    const int ty = tid >> 4, tx = tid & 15;
    const int bh = blockIdx.x;
    const int h = bh & (H_ - 1);

    const float4* W4 = (const float4*)(W + h * D_ * D_);
    const float4* A4 = (const float4*)(A + bh * D_ * D_);
#pragma unroll
    for (int it = 0; it < 4; ++it) {
        int idx = tid + it * 256;
        int r = idx >> 4, c = idx & 15;
        *(float4*)&s0[r * LDST + c * 4] = W4[idx];
        *(float4*)&s1[r * LDST + c * 4] = A4[idx];
    }
    __syncthreads();

    float acc[4][4] = {};
    for (int d = 0; d < D_; ++d) {
        float4 a4 = *(const float4*)&s1[d * LDST + tx * 4];
#pragma unroll
        for (int i = 0; i < 4; ++i) {
            float w = s0[(ty * 4 + i) * LDST + d];
            acc[i][0] += w * a4.x; acc[i][1] += w * a4.y;
            acc[i][2] += w * a4.z; acc[i][3] += w * a4.w;
        }
    }
    __syncthreads();

#pragma unroll
    for (int i = 0; i < 4; ++i) {
        int f = ty * 4 + i;
        float4 b4 = *(const float4*)&bb[(h * D_ + f) * D_ + tx * 4];
        float4 p4 = *(const float4*)&pw[(h * D_ + f) * D_ + tx * 4];
        float vb[4] = {b4.x, b4.y, b4.z, b4.w};
        float vp[4] = {p4.x, p4.y, p4.z, p4.w};
#pragma unroll
        for (int j = 0; j < 4; ++j) {
            float aw = fmaxf(acc[i][j] + vb[j], 0.f) + 1e-9f;
            s0[f * LDST + tx * 4 + j] = powf(aw, vp[j]);
        }
    }
    const float4* av4 = (const float4*)(av + h * D_ * D_);
#pragma unroll
    for (int it = 0; it < 4; ++it) {
        int idx = tid + it * 256;
        int r = idx >> 4, c = idx & 15;
        *(float4*)&s1[r * LDST + c * 4] = av4[idx];
    }
    __syncthreads();

    float acc2[4][4] = {};
    for (int d = 0; d < D_; ++d) {
        float4 a4 = *(const float4*)&s0[d * LDST + tx * 4];
#pragma unroll
        for (int i = 0; i < 4; ++i) {
            float w = s1[(ty * 4 + i) * LDST + d];
            acc2[i][0] += w * a4.x; acc2[i][1] += w * a4.y;
            acc2[i][2] += w * a4.z; acc2[i][3] += w * a4.w;
        }
    }
#pragma unroll
    for (int i = 0; i < 4; ++i) {
        int f = ty * 4 + i;
        float4 ba4 = *(const float4*)&ba[(h * D_ + f) * D_ + tx * 4];
        float4 o = make_float4(acc2[i][0] + ba4.x, acc2[i][1] + ba4.y,
                               acc2[i][2] + ba4.z, acc2[i][3] + ba4.w);
        *(float4*)&avAp[bh * D_ * D_ + f * D_ + tx * 4] = o;
    }
}

// ---------------------------------------------------------------------------
// Kernel 2: MFMA flash attention, f16 hi/lo split for QK^T, f16 for P/V.
// 2 waves/block, QBLK=64 (each wave 32 q-rows = 2x 16x16 m-subtiles).
// LDS regions (manual offsets, prep phase overlays K-loop regions):
//   [0,8192)      sKh  [64][64] f16, XOR swizzle byte^=((r&7)<<4)
//   [8192,16384)  sKl  same
//   [16384,24576) sVT  [64][64] f16 (V transposed), byte^=(((r&7)^(r>>3&7))<<4)
//   [24576,32768) sP   [64][64] f16, K-style swizzle
//   [32768,33024) sMask 64 f32
//   prep overlay: AVP f32[64][68]@0, HIN f32[64][68]@17408, QP f32[64][68]@34816
// ---------------------------------------------------------------------------
#define KH_OFF 0
#define KL_OFF 8192
#define VT_OFF 16384
#define P_OFF  24576
#define MK_OFF 32768
#define HIN_OFF 17408
#define QP_OFF  34816
#define SMEM_BYTES 52224

__global__ __launch_bounds__(128) void flash2(
    const float* __restrict__ Hin, const float* __restrict__ Hk,
    const float* __restrict__ Hv, const float* __restrict__ maskg,
    const float* __restrict__ avAp, float* __restrict__ out)
{
    __shared__ __align__(16) char smem[SMEM_BYTES];
    float* AVP = (float*)smem;                 // [64][68]
    float* HIN = (float*)(smem + HIN_OFF);     // [64][68]
    float* QP  = (float*)(smem + QP_OFF);      // [64][68]
    float* MASKS = (float*)(smem + MK_OFF);

    const int tid = threadIdx.x;
    const int wave = tid >> 6, lane = tid & 63;
    const int l15 = lane & 15, lg = lane >> 4;
    const int qt = blockIdx.x, bh = blockIdx.y;
    const int b = bh >> 3;
    const size_t base = (size_t)bh * S_ * D_;
    const int q0 = qt * TS;

    // ---- Phase A: Qp = Hin_tile @ avAp (f32, in LDS) ----
    {
        const float4* a4 = (const float4*)(avAp + bh * D_ * D_);
        const float4* h4 = (const float4*)(Hin + base + (size_t)q0 * D_);
#pragma unroll
        for (int i = 0; i < 8; ++i) {
            int f = tid + i * 128;
            int r = f >> 4, c = (f & 15) * 4;
            *(float4*)&AVP[r * LDST + c] = a4[f];
            *(float4*)&HIN[r * LDST + c] = h4[f];
        }
    }
    __syncthreads();
    {
        const int tx = tid & 15, ty = tid >> 4;   // ty 0..7, 8 rows each
        float acc[8][4] = {};
        for (int d = 0; d < D_; ++d) {
            float4 av = *(const float4*)&AVP[d * LDST + tx * 4];
#pragma unroll
            for (int rr = 0; rr < 8; ++rr) {
                float h = HIN[(ty * 8 + rr) * LDST + d];
                acc[rr][0] += h * av.x; acc[rr][1] += h * av.y;
                acc[rr][2] += h * av.z; acc[rr][3] += h * av.w;
            }
        }
#pragma unroll
        for (int rr = 0; rr < 8; ++rr)
            *(float4*)&QP[(ty * 8 + rr) * LDST + tx * 4] =
                make_float4(acc[rr][0], acc[rr][1], acc[rr][2], acc[rr][3]);
    }
    __syncthreads();

    // ---- extract Q A-frags (x0.125 folded in), hi/lo f16 ----
    f16x8 qAh[2][2], qAl[2][2];
#pragma unroll
    for (int ms = 0; ms < 2; ++ms)
#pragma unroll
        for (int kc = 0; kc < 2; ++kc) {
            int row = wave * 32 + ms * 16 + l15;
            int k0 = kc * 32 + lg * 8;
            float4 v0 = *(const float4*)&QP[row * LDST + k0];
            float4 v1 = *(const float4*)&QP[row * LDST + k0 + 4];
            float xs[8] = {v0.x, v0.y, v0.z, v0.w, v1.x, v1.y, v1.z, v1.w};
#pragma unroll
            for (int j = 0; j < 8; ++j) {
                float x = xs[j] * 0.125f;
                _Float16 hh = (_Float16)x;
                qAh[ms][kc][j] = hh;
                qAl[ms][kc][j] = (_Float16)(x - (float)hh);
            }
        }
    __syncthreads();   // prep regions free for K-loop staging

    float mrun[8], lrun[8];
    f32x4 o[2][4];
#pragma unroll
    for (int i = 0; i < 8; ++i) { mrun[i] = -INFINITY; lrun[i] = 0.f; }
#pragma unroll
    for (int ms = 0; ms < 2; ++ms)
#pragma unroll
        for (int ns = 0; ns < 4; ++ns) o[ms][ns] = (f32x4){0.f, 0.f, 0.f, 0.f};

    for (int kt = 0; kt < S_ / TS; ++kt) {
        // -- stage K (hi/lo) and V^T into swizzled LDS --
        if (tid < 64) MASKS[tid] = -1e9f * maskg[b * S_ + kt * TS + tid];
        const float* Kg = Hk + base + (size_t)kt * TS * D_;
        const float* Vg = Hv + base + (size_t)kt * TS * D_;
#pragma unroll
        for (int i = 0; i < 4; ++i) {
            int c = tid + i * 128;
            int r = c >> 3, c8 = c & 7;
            float4 f0 = *(const float4*)(Kg + c * 8);
            float4 f1 = *(const float4*)(Kg + c * 8 + 4);
            float xs[8] = {f0.x, f0.y, f0.z, f0.w, f1.x, f1.y, f1.z, f1.w};
            f16x8 h, l;
#pragma unroll
            for (int e = 0; e < 8; ++e) {
                _Float16 hh = (_Float16)xs[e];
                h[e] = hh; l[e] = (_Float16)(xs[e] - (float)hh);
            }
            int byte = (r * 128 + c8 * 16) ^ ((r & 7) << 4);
            *(f16x8*)(smem + KH_OFF + byte) = h;
            *(f16x8*)(smem + KL_OFF + byte) = l;

            float4 w0 = *(const float4*)(Vg + c * 8);
            float4 w1 = *(const float4*)(Vg + c * 8 + 4);
            float vs[8] = {w0.x, w0.y, w0.z, w0.w, w1.x, w1.y, w1.z, w1.w};
#pragma unroll
            for (int e = 0; e < 8; ++e) {
                int vr = c8 * 8 + e;           // VT row = V col
                int vb = (vr * 128 + r * 2) ^
                         ((((vr & 7) ^ ((vr >> 3) & 7)) << 4));
                *(_Float16*)(smem + VT_OFF + vb) = (_Float16)vs[e];
            }
        }
        __syncthreads();

        // -- scores: S = (Q/8) @ K^T, 3-term hi/lo --
        f32x4 s[2][4];
#pragma unroll
        for (int ms = 0; ms < 2; ++ms)
#pragma unroll
            for (int ns = 0; ns < 4; ++ns) s[ms][ns] = (f32x4){0.f, 0.f, 0.f, 0.f};
#pragma unroll
        for (int ns = 0; ns < 4; ++ns)
#pragma unroll
            for (int kc = 0; kc < 2; ++kc) {
                int row = ns * 16 + l15;
                int byte = (row * 128 + kc * 64 + lg * 16) ^ ((row & 7) << 4);
                f16x8 kh = *(const f16x8*)(smem + KH_OFF + byte);
                f16x8 kl = *(const f16x8*)(smem + KL_OFF + byte);
#pragma unroll
                for (int ms = 0; ms < 2; ++ms) {
                    s[ms][ns] = __builtin_amdgcn_mfma_f32_16x16x32_f16(qAh[ms][kc], kh, s[ms][ns], 0, 0, 0);
                    s[ms][ns] = __builtin_amdgcn_mfma_f32_16x16x32_f16(qAl[ms][kc], kh, s[ms][ns], 0, 0, 0);
                    s[ms][ns] = __builtin_amdgcn_mfma_f32_16x16x32_f16(qAh[ms][kc], kl, s[ms][ns], 0, 0, 0);
                }
            }

        // -- leaky + mask + online softmax (rows live in 16-lane groups) --
        float mk[4];
#pragma unroll
        for (int ns = 0; ns < 4; ++ns) mk[ns] = MASKS[ns * 16 + l15];
        float scs[2][4];
#pragma unroll
        for (int ms = 0; ms < 2; ++ms)
#pragma unroll
            for (int r = 0; r < 4; ++r) {
                float v[4];
#pragma unroll
                for (int ns = 0; ns < 4; ++ns) {
                    float x = s[ms][ns][r];
                    x = (x > 0.f) ? x : 0.2f * x;
                    v[ns] = x + mk[ns];
                }
                float m0 = fmaxf(fmaxf(v[0], v[1]), fmaxf(v[2], v[3]));
#pragma unroll
                for (int off = 1; off < 16; off <<= 1)
                    m0 = fmaxf(m0, __shfl_xor(m0, off, 64));
                int idx = ms * 4 + r;
                float mnew = fmaxf(mrun[idx], m0);
                float sc = __expf(mrun[idx] - mnew);
                mrun[idx] = mnew;
                float rs = 0.f;
                float p[4];
#pragma unroll
                for (int ns = 0; ns < 4; ++ns) { p[ns] = __expf(v[ns] - mnew); rs += p[ns]; }
#pragma unroll
                for (int off = 1; off < 16; off <<= 1)
                    rs += __shfl_xor(rs, off, 64);
                lrun[idx] = lrun[idx] * sc + rs;
                scs[ms][r] = sc;
                int qrow = wave * 32 + ms * 16 + lg * 4 + r;
#pragma unroll
                for (int ns = 0; ns < 4; ++ns) {
                    int pb = (qrow * 128 + (ns * 16 + l15) * 2) ^ ((qrow & 7) << 4);
                    *(_Float16*)(smem + P_OFF + pb) = (_Float16)p[ns];
                }
            }
        // rescale O
#pragma unroll
        for (int ms = 0; ms < 2; ++ms)
#pragma unroll
            for (int ns = 0; ns < 4; ++ns)
#pragma unroll
                for (int r = 0; r < 4; ++r) o[ms][ns][r] *= scs[ms][r];
        __syncthreads();   // P visible to whole wave; K/VT reads done next phase

        // -- O += P @ V --
#pragma unroll
        for (int kc = 0; kc < 2; ++kc) {
            f16x8 pf[2];
#pragma unroll
            for (int ms = 0; ms < 2; ++ms) {
                int prow = wave * 32 + ms * 16 + l15;
                int pb = (prow * 128 + kc * 64 + lg * 16) ^ ((prow & 7) << 4);
                pf[ms] = *(const f16x8*)(smem + P_OFF + pb);
            }
#pragma unroll
            for (int ns = 0; ns < 4; ++ns) {
                int vrow = ns * 16 + l15;
                int vb = (vrow * 128 + kc * 64 + lg * 16) ^
                         ((((vrow & 7) ^ ((vrow >> 3) & 7)) << 4));
                f16x8 vf = *(const f16x8*)(smem + VT_OFF + vb);
#pragma unroll
                for (int ms = 0; ms < 2; ++ms)
                    o[ms][ns] = __builtin_amdgcn_mfma_f32_16x16x32_f16(pf[ms], vf, o[ms][ns], 0, 0, 0);
            }
        }
        __syncthreads();   // tile fully consumed before next staging
    }

    // ---- epilogue: normalize, relu, store ----
#pragma unroll
    for (int ms = 0; ms < 2; ++ms)
#pragma unroll
        for (int r = 0; r < 4; ++r) {
            float inv = 1.f / lrun[ms * 4 + r];
            int row = q0 + wave * 32 + ms * 16 + lg * 4 + r;
#pragma unroll
            for (int ns = 0; ns < 4; ++ns)
                out[base + (size_t)row * D_ + ns * 16 + l15] =
                    fmaxf(o[ms][ns][r] * inv, 0.f);
        }
}

extern "C" void kernel_launch(void* const* d_in, const int* in_sizes, int n_in,
                              void* d_out, int out_size, void* d_ws, size_t ws_size,
                              hipStream_t stream) {
    const float* Hin  = (const float*)d_in[0];
    const float* Hk   = (const float*)d_in[1];
    const float* Hv   = (const float*)d_in[2];
    const float* A    = (const float*)d_in[3];
    const float* mask = (const float*)d_in[4];
    const float* W    = (const float*)d_in[5];
    const float* bb   = (const float*)d_in[6];
    const float* av   = (const float*)d_in[7];
    const float* ba   = (const float*)d_in[8];
    const float* pw   = (const float*)d_in[9];
    float* out = (float*)d_out;
    float* ws  = (float*)d_ws;   // avAp: 256 KB

    prep_avAp<<<B_ * H_, 256, 0, stream>>>(A, W, bb, av, ba, pw, ws);
    flash2<<<dim3(S_ / TS, B_ * H_), 128, 0, stream>>>(Hin, Hk, Hv, mask, ws, out);
}

// Round 9
// 185.927 us; speedup vs baseline: 2.1143x; 1.6504x over previous
//
#include <hip/hip_runtime.h>
#include <cmath>

#define B_ 2
#define H_ 8
#define S_ 2048
#define D_ 64
#define TS 64
#define NT (S_ / TS)
#define LDST 68

typedef __attribute__((ext_vector_type(8))) _Float16 f16x8;
typedef __attribute__((ext_vector_type(4))) float f32x4;

// ---------------------------------------------------------------------------
// Kernel 1: avAp = a_vec @ ((relu(W@A+b)+eps)^pw) + ba
// ---------------------------------------------------------------------------
__global__ __launch_bounds__(256) void prep_avAp(
    const float* __restrict__ A, const float* __restrict__ W,
    const float* __restrict__ bb, const float* __restrict__ av,
    const float* __restrict__ ba, const float* __restrict__ pw,
    float* __restrict__ avAp)
{
    __shared__ float s0[TS * LDST];
    __shared__ float s1[TS * LDST];
    const int tid = threadIdx.x;
    const int ty = tid >> 4, tx = tid & 15;
    const int bh = blockIdx.x;
    const int h = bh & (H_ - 1);

    const float4* W4 = (const float4*)(W + h * D_ * D_);
    const float4* A4 = (const float4*)(A + bh * D_ * D_);
#pragma unroll
    for (int it = 0; it < 4; ++it) {
        int idx = tid + it * 256;
        int r = idx >> 4, c = idx & 15;
        *(float4*)&s0[r * LDST + c * 4] = W4[idx];
        *(float4*)&s1[r * LDST + c * 4] = A4[idx];
    }
    __syncthreads();

    float acc[4][4] = {};
    for (int d = 0; d < D_; ++d) {
        float4 a4 = *(const float4*)&s1[d * LDST + tx * 4];
#pragma unroll
        for (int i = 0; i < 4; ++i) {
            float w = s0[(ty * 4 + i) * LDST + d];
            acc[i][0] += w * a4.x; acc[i][1] += w * a4.y;
            acc[i][2] += w * a4.z; acc[i][3] += w * a4.w;
        }
    }
    __syncthreads();

#pragma unroll
    for (int i = 0; i < 4; ++i) {
        int f = ty * 4 + i;
        float4 b4 = *(const float4*)&bb[(h * D_ + f) * D_ + tx * 4];
        float4 p4 = *(const float4*)&pw[(h * D_ + f) * D_ + tx * 4];
        float vb[4] = {b4.x, b4.y, b4.z, b4.w};
        float vp[4] = {p4.x, p4.y, p4.z, p4.w};
#pragma unroll
        for (int j = 0; j < 4; ++j) {
            float aw = fmaxf(acc[i][j] + vb[j], 0.f) + 1e-9f;
            s0[f * LDST + tx * 4 + j] = exp2f(vp[j] * __log2f(aw));
        }
    }
    const float4* av4 = (const float4*)(av + h * D_ * D_);
#pragma unroll
    for (int it = 0; it < 4; ++it) {
        int idx = tid + it * 256;
        int r = idx >> 4, c = idx & 15;
        *(float4*)&s1[r * LDST + c * 4] = av4[idx];
    }
    __syncthreads();

    float acc2[4][4] = {};
    for (int d = 0; d < D_; ++d) {
        float4 a4 = *(const float4*)&s0[d * LDST + tx * 4];
#pragma unroll
        for (int i = 0; i < 4; ++i) {
            float w = s1[(ty * 4 + i) * LDST + d];
            acc2[i][0] += w * a4.x; acc2[i][1] += w * a4.y;
            acc2[i][2] += w * a4.z; acc2[i][3] += w * a4.w;
        }
    }
#pragma unroll
    for (int i = 0; i < 4; ++i) {
        int f = ty * 4 + i;
        float4 ba4 = *(const float4*)&ba[(h * D_ + f) * D_ + tx * 4];
        float4 o = make_float4(acc2[i][0] + ba4.x, acc2[i][1] + ba4.y,
                               acc2[i][2] + ba4.z, acc2[i][3] + ba4.w);
        *(float4*)&avAp[bh * D_ * D_ + f * D_ + tx * 4] = o;
    }
}

// ---------------------------------------------------------------------------
// Kernel 2 "flash4": flash2's replay-proven 3-barrier single-buffer skeleton
// + 4 waves/block + register prefetch of next K/V tile + intra-wave P.
// LDS map (58368 B, no region ever reused for two purposes):
//   KH@0(8K)  KL@8192(8K)  VT@16384(8K)  P@24576(4x2K)  MROW@32768(8K)
//   QP@40960(17408)   prep-only: AVP@0(17408) HIN@17408(17408)
// Barriers/tile: [1] P visible  [2] all tile reads drained  [3] staging visible
// ---------------------------------------------------------------------------
#define KH_S 0
#define KL_S 8192
#define VT_S 16384
#define P_S  24576
#define MROW_S 32768
#define QP_S 40960
#define AVP_S 0
#define HIN_S 17408
#define SMEM_SZ 58368

__global__ __launch_bounds__(256) void flash4(
    const float* __restrict__ Hin, const float* __restrict__ Hk,
    const float* __restrict__ Hv, const float* __restrict__ maskg,
    const float* __restrict__ avAp, float* __restrict__ out)
{
    __shared__ __align__(16) char smem[SMEM_SZ];
    float* AVP = (float*)(smem + AVP_S);
    float* HIN = (float*)(smem + HIN_S);
    float* QP  = (float*)(smem + QP_S);
    float* MROW = (float*)(smem + MROW_S);

    const int tid = threadIdx.x;
    const int wave = tid >> 6, lane = tid & 63;
    const int l15 = lane & 15, lg = lane >> 4;
    const int qt = blockIdx.x, bh = blockIdx.y;
    const int b = bh >> 3;
    const size_t base = (size_t)bh * S_ * D_;
    const int q0 = qt * TS;

    // ---- Phase A: Qp = Hin_tile @ avAp (f32 in LDS) ----
    {
        const float4* a4 = (const float4*)(avAp + bh * D_ * D_);
        const float4* h4 = (const float4*)(Hin + base + (size_t)q0 * D_);
#pragma unroll
        for (int i = 0; i < 4; ++i) {
            int f = tid + i * 256;
            int r = f >> 4, c = (f & 15) * 4;
            *(float4*)&AVP[r * LDST + c] = a4[f];
            *(float4*)&HIN[r * LDST + c] = h4[f];
        }
    }
    __syncthreads();
    {
        const int tx = tid & 15, ty = tid >> 4;
        float acc[4][4] = {};
        for (int d = 0; d < D_; ++d) {
            float4 av = *(const float4*)&AVP[d * LDST + tx * 4];
#pragma unroll
            for (int rr = 0; rr < 4; ++rr) {
                float h = HIN[(ty * 4 + rr) * LDST + d];
                acc[rr][0] += h * av.x; acc[rr][1] += h * av.y;
                acc[rr][2] += h * av.z; acc[rr][3] += h * av.w;
            }
        }
#pragma unroll
        for (int rr = 0; rr < 4; ++rr)
            *(float4*)&QP[(ty * 4 + rr) * LDST + tx * 4] =
                make_float4(acc[rr][0], acc[rr][1], acc[rr][2], acc[rr][3]);
    }
    __syncthreads();

    // ---- extract Q A-frags (x0.125 folded), hi/lo f16 (QP never overwritten) ----
    f16x8 qAh[2], qAl[2];
#pragma unroll
    for (int kc = 0; kc < 2; ++kc) {
        int row = wave * 16 + l15;
        int k0 = kc * 32 + lg * 8;
        float4 v0 = *(const float4*)&QP[row * LDST + k0];
        float4 v1 = *(const float4*)&QP[row * LDST + k0 + 4];
        float xs[8] = {v0.x, v0.y, v0.z, v0.w, v1.x, v1.y, v1.z, v1.w};
#pragma unroll
        for (int j = 0; j < 8; ++j) {
            float x = xs[j] * 0.125f;
            _Float16 hh = (_Float16)x;
            qAh[kc][j] = hh;
            qAl[kc][j] = (_Float16)(x - (float)hh);
        }
    }

    // ---- stage helpers (single buffer) ----
    float4 kreg[2][2], vreg[2][2];
    auto stage_load = [&](int kt) {
        const float* Kg = Hk + base + (size_t)kt * TS * D_;
        const float* Vg = Hv + base + (size_t)kt * TS * D_;
#pragma unroll
        for (int i = 0; i < 2; ++i) {
            int c = tid + i * 256;
            kreg[i][0] = *(const float4*)(Kg + c * 8);
            kreg[i][1] = *(const float4*)(Kg + c * 8 + 4);
            vreg[i][0] = *(const float4*)(Vg + c * 8);
            vreg[i][1] = *(const float4*)(Vg + c * 8 + 4);
        }
    };
    auto stage_write = [&]() {
#pragma unroll
        for (int i = 0; i < 2; ++i) {
            int c = tid + i * 256;
            int r = c >> 3, c8 = c & 7;
            float xs[8] = {kreg[i][0].x, kreg[i][0].y, kreg[i][0].z, kreg[i][0].w,
                           kreg[i][1].x, kreg[i][1].y, kreg[i][1].z, kreg[i][1].w};
            f16x8 h, l;
#pragma unroll
            for (int e = 0; e < 8; ++e) {
                _Float16 hh = (_Float16)xs[e];
                h[e] = hh; l[e] = (_Float16)(xs[e] - (float)hh);
            }
            int byte = (r * 128 + c8 * 16) ^ ((r & 7) << 4);
            *(f16x8*)(smem + KH_S + byte) = h;
            *(f16x8*)(smem + KL_S + byte) = l;
            float vs[8] = {vreg[i][0].x, vreg[i][0].y, vreg[i][0].z, vreg[i][0].w,
                           vreg[i][1].x, vreg[i][1].y, vreg[i][1].z, vreg[i][1].w};
#pragma unroll
            for (int e = 0; e < 8; ++e) {
                int vr = c8 * 8 + e;
                int vb = (vr * 128 + r * 2) ^
                         ((((vr & 7) ^ ((vr >> 3) & 7)) << 4));
                *(_Float16*)(smem + VT_S + vb) = (_Float16)vs[e];
            }
        }
    };

    // ---- prologue: tile 0 staged + mask row ----
    stage_load(0);
    stage_write();
    for (int i = tid; i < S_; i += 256) MROW[i] = -1e9f * maskg[b * S_ + i];
    __syncthreads();

    float mrun[4], lrun[4];
    f32x4 o[4];
#pragma unroll
    for (int i = 0; i < 4; ++i) {
        mrun[i] = -INFINITY; lrun[i] = 0.f;
        o[i] = (f32x4){0.f, 0.f, 0.f, 0.f};
    }

    for (int kt = 0; kt < NT; ++kt) {
        if (kt + 1 < NT) stage_load(kt + 1);   // prefetch next tile into regs

        // -- QK^T, 3-term hi/lo --
        f32x4 s[4];
#pragma unroll
        for (int ns = 0; ns < 4; ++ns) s[ns] = (f32x4){0.f, 0.f, 0.f, 0.f};
        __builtin_amdgcn_s_setprio(1);
#pragma unroll
        for (int ns = 0; ns < 4; ++ns)
#pragma unroll
            for (int kc = 0; kc < 2; ++kc) {
                int row = ns * 16 + l15;
                int byte = (row * 128 + kc * 64 + lg * 16) ^ ((row & 7) << 4);
                f16x8 kh = *(const f16x8*)(smem + KH_S + byte);
                f16x8 kl = *(const f16x8*)(smem + KL_S + byte);
                s[ns] = __builtin_amdgcn_mfma_f32_16x16x32_f16(qAh[kc], kh, s[ns], 0, 0, 0);
                s[ns] = __builtin_amdgcn_mfma_f32_16x16x32_f16(qAl[kc], kh, s[ns], 0, 0, 0);
                s[ns] = __builtin_amdgcn_mfma_f32_16x16x32_f16(qAh[kc], kl, s[ns], 0, 0, 0);
            }
        __builtin_amdgcn_s_setprio(0);

        // -- leaky + mask + online softmax (row = lg*4+r, col = ns*16+l15) --
        float mk[4];
#pragma unroll
        for (int ns = 0; ns < 4; ++ns) mk[ns] = MROW[kt * 64 + ns * 16 + l15];
        float scs[4];
#pragma unroll
        for (int r = 0; r < 4; ++r) {
            float v[4];
#pragma unroll
            for (int ns = 0; ns < 4; ++ns) {
                float x = s[ns][r];
                x = (x > 0.f) ? x : 0.2f * x;
                v[ns] = x + mk[ns];
            }
            float m0 = fmaxf(fmaxf(v[0], v[1]), fmaxf(v[2], v[3]));
#pragma unroll
            for (int off = 1; off < 16; off <<= 1)
                m0 = fmaxf(m0, __shfl_xor(m0, off, 64));
            float mnew = fmaxf(mrun[r], m0);
            float sc = __expf(mrun[r] - mnew);
            mrun[r] = mnew;
            float rs = 0.f;
            float p[4];
#pragma unroll
            for (int ns = 0; ns < 4; ++ns) { p[ns] = __expf(v[ns] - mnew); rs += p[ns]; }
#pragma unroll
            for (int off = 1; off < 16; off <<= 1)
                rs += __shfl_xor(rs, off, 64);
            lrun[r] = lrun[r] * sc + rs;
            scs[r] = sc;
            int prow = lg * 4 + r;
#pragma unroll
            for (int ns = 0; ns < 4; ++ns) {
                int pb = (prow * 128 + (ns * 16 + l15) * 2) ^ ((prow & 7) << 4);
                *(_Float16*)(smem + P_S + wave * 2048 + pb) = (_Float16)p[ns];
            }
        }
#pragma unroll
        for (int ns = 0; ns < 4; ++ns)
#pragma unroll
            for (int r = 0; r < 4; ++r) o[ns][r] *= scs[r];

        __syncthreads();   // [1] P visible

        // -- O += P @ V --
        __builtin_amdgcn_s_setprio(1);
#pragma unroll
        for (int kc = 0; kc < 2; ++kc) {
            int pb = (l15 * 128 + kc * 64 + lg * 16) ^ ((l15 & 7) << 4);
            f16x8 pf = *(const f16x8*)(smem + P_S + wave * 2048 + pb);
#pragma unroll
            for (int ns = 0; ns < 4; ++ns) {
                int vrow = ns * 16 + l15;
                int vb = (vrow * 128 + kc * 64 + lg * 16) ^
                         ((((vrow & 7) ^ ((vrow >> 3) & 7)) << 4));
                f16x8 vf = *(const f16x8*)(smem + VT_S + vb);
                o[ns] = __builtin_amdgcn_mfma_f32_16x16x32_f16(pf, vf, o[ns], 0, 0, 0);
            }
        }
        __builtin_amdgcn_s_setprio(0);

        __syncthreads();   // [2] all reads of tile kt drained

        if (kt + 1 < NT) stage_write();  // overwrite single buffer with tile kt+1

        __syncthreads();   // [3] staging visible
    }

    // ---- epilogue ----
#pragma unroll
    for (int r = 0; r < 4; ++r) {
        float inv = 1.f / lrun[r];
        int row = q0 + wave * 16 + lg * 4 + r;
#pragma unroll
        for (int ns = 0; ns < 4; ++ns)
            out[base + (size_t)row * D_ + ns * 16 + l15] =
                fmaxf(o[ns][r] * inv, 0.f);
    }
}

extern "C" void kernel_launch(void* const* d_in, const int* in_sizes, int n_in,
                              void* d_out, int out_size, void* d_ws, size_t ws_size,
                              hipStream_t stream) {
    const float* Hin  = (const float*)d_in[0];
    const float* Hk   = (const float*)d_in[1];
    const float* Hv   = (const float*)d_in[2];
    const float* A    = (const float*)d_in[3];
    const float* mask = (const float*)d_in[4];
    const float* W    = (const float*)d_in[5];
    const float* bb   = (const float*)d_in[6];
    const float* av   = (const float*)d_in[7];
    const float* ba   = (const float*)d_in[8];
    const float* pw   = (const float*)d_in[9];
    float* out = (float*)d_out;
    float* ws  = (float*)d_ws;

    prep_avAp<<<B_ * H_, 256, 0, stream>>>(A, W, bb, av, ba, pw, ws);
    flash4<<<dim3(NT, B_ * H_), 256, 0, stream>>>(Hin, Hk, Hv, mask, ws, out);
}